// Round 9
// baseline (237.337 us; speedup 1.0000x reference)
//
#include <hip/hip_runtime.h>

#define N_NODES 100000
#define N_EDGES 1600000
#define IN_DIM 32
#define HID_DIM 64
#define OUT_DIM 8
#define BK 64                         // dst nodes per bucket
#define NBKT ((N_NODES + BK - 1) / BK)    // 1563
#define QC 1280                       // per-bucket queue cap (mean 1024, +8 sigma)
#define CHUNK 4096                    // edges per k_part2 block
#define NCHUNK ((N_EDGES + CHUNK - 1) / CHUNK)   // 391

typedef unsigned short u16;
typedef unsigned int u32;
typedef unsigned long long ull;

__device__ __forceinline__ float bf2f(u16 v) {
    return __uint_as_float(((u32)v) << 16);
}

__device__ __forceinline__ u16 f2bf(float f) {
    u32 u = __float_as_uint(f);
    u32 lsb = (u >> 16) & 1u;
    u += 0x7fffu + lsb;
    return (u16)(u >> 16);
}

__device__ __forceinline__ float ldf(const void* p, size_t i, int bf) {
    return bf ? bf2f(((const u16*)p)[i]) : ((const float*)p)[i];
}

// ---- Phase A (R5/R8-proven) + NEW: repack x into contiguous dim-halves
//      xlo/xhi (bf16: 3.2MB each -> per-XCD-L2-resident gather targets). ----
__global__ __launch_bounds__(256) void k_part2(
    const int* __restrict__ ei, const u32* __restrict__ xw,
    const void* __restrict__ W1l, const void* __restrict__ b1,
    const void* __restrict__ W1r,
    const void* __restrict__ W2l, const void* __restrict__ b2,
    const void* __restrict__ W2r,
    int* __restrict__ qcnt, u32* __restrict__ qbuf,
    float* __restrict__ tW1l, float* __restrict__ tW1r,
    float* __restrict__ tW2l, float* __restrict__ tW2r,
    float* __restrict__ tb1, float* __restrict__ tb2,
    u32* __restrict__ xlo, u32* __restrict__ xhi)
{
    __shared__ int shv, bfv;
    __shared__ int hist[NBKT], gbase[NBKT], lcur[NBKT];   // 18.8 KB
    int t = threadIdx.x;
    if (t < 64) {   // proven dtype probe, executed per block (same data)
        int v = ei[2 * t + 1];
        ull m1 = __ballot(v == 0);
        u32 wd = xw[t];
        u32 b = (wd >> 8) & 0x7fu;
        ull m2 = __ballot(b >= 0x38u && b <= 0x41u);
        if (t == 0) {
            shv = (m1 == ~0ULL) ? 1 : 0;
            bfv = (__popcll(m2) >= 56) ? 1 : 0;
        }
    }
    for (int i = t; i < NBKT; i += 256) { hist[i] = 0; lcur[i] = 0; }
    __syncthreads();
    int sh = shv, bf = bfv;

    // repack x into dim-halves (pure u32 word copies, dtype preserved;
    // R1-proven indexing). nt stores: don't pollute L2 during k_part2.
    if (bf) {
        for (int i = blockIdx.x * 256 + t; i < N_NODES * 8; i += NCHUNK * 256) {
            int n2 = i >> 3, k = i & 7;
            __builtin_nontemporal_store(xw[n2 * 16 + k], &xlo[i]);
            __builtin_nontemporal_store(xw[n2 * 16 + 8 + k], &xhi[i]);
        }
    } else {
        for (int i = blockIdx.x * 256 + t; i < N_NODES * 16; i += NCHUNK * 256) {
            int n2 = i >> 4, k = i & 15;
            __builtin_nontemporal_store(xw[n2 * 32 + k], &xlo[i]);
            __builtin_nontemporal_store(xw[n2 * 32 + 16 + k], &xhi[i]);
        }
    }

    if (blockIdx.x < 16) {        // weight transpose duty (R11-proven indexing)
        for (int i = blockIdx.x * 256 + t; i < HID_DIM * IN_DIM; i += 16 * 256) {
            int o = i / IN_DIM, k = i % IN_DIM;
            tW1l[k * HID_DIM + o] = ldf(W1l, i, bf);
            tW1r[k * HID_DIM + o] = ldf(W1r, i, bf);
        }
        for (int i = blockIdx.x * 256 + t; i < OUT_DIM * HID_DIM; i += 16 * 256) {
            int o = i / HID_DIM, k = i % HID_DIM;
            tW2l[k * OUT_DIM + o] = ldf(W2l, i, bf);
            tW2r[k * OUT_DIM + o] = ldf(W2r, i, bf);
        }
        if (blockIdx.x == 0) {
            if (t < HID_DIM) tb1[t] = ldf(b1, t, bf);
            if (t < OUT_DIM) tb2[t] = ldf(b2, t, bf);
        }
    }

    // edge partition (register-staged, R10-proven shape)
    int e0 = blockIdx.x * CHUNK;
    int myd[16], mys[16];
    #pragma unroll
    for (int i = 0; i < 16; i++) {
        int e = e0 + i * 256 + t;
        if (e < N_EDGES) {
            size_t off = (size_t)e << sh;
            mys[i] = ei[off];
            int d = ei[((size_t)N_EDGES << sh) + off];
            myd[i] = d;
            atomicAdd(&hist[d >> 6], 1);
        } else myd[i] = -1;
    }
    __syncthreads();
    for (int i = t; i < NBKT; i += 256) {
        int h = hist[i];
        gbase[i] = h ? atomicAdd(&qcnt[i], h) : 0;
    }
    __syncthreads();
    #pragma unroll
    for (int i = 0; i < 16; i++) {
        int d = myd[i];
        if (d >= 0) {
            int bk = d >> 6;
            int p = gbase[bk] + atomicAdd(&lcur[bk], 1);
            if (p < QC)
                qbuf[(size_t)bk * QC + p] = ((u32)mys[i] << 6) | (u32)(d & 63);
        }
    }
}

// ---- Layer 1: one 64-node bucket per block (R8-proven shell).
//      NEW: gather runs TWICE over the sorted LDS lists — pass-lo reads the
//      L2-resident xlo (dims 0-15), pass-hi reads xhi — accumulating into
//      LDS agg[64][32]. R8 measured the gather pegged at ~0.9TB/s on the
//      L2-miss path (perf invariant to occupancy config); 3.2MB halves fit
//      a 4MiB per-XCD L2 so steady-state gathers become L2 hits.
//      qbuf reads nontemporal (don't evict the gather target). ----
__global__ __launch_bounds__(256, 4) void k_l1(
    const void* __restrict__ xlo, const void* __restrict__ xhi,
    const void* __restrict__ x,
    const int* __restrict__ qcnt, const u32* __restrict__ qbuf,
    const float* __restrict__ tW1l, const float* __restrict__ tW1r,
    const float* __restrict__ tW2l, const float* __restrict__ tW2r,
    const float* __restrict__ tb1, const float* __restrict__ tb2,
    u16* __restrict__ gbuf, float* __restrict__ rbuf,
    const u32* __restrict__ xw)
{
    __shared__ int hist[BK], pos[BK], pcur[BK];   // 0.75 KB
    __shared__ u32 srt[QC];                 // 5.1 KB sorted src lists
    __shared__ float xs[BK][IN_DIM];        // 8 KB self rows (f32)
    __shared__ float agg[BK][IN_DIM];       // 8 KB neighbor sums (f32)
    __shared__ float hb[8][HID_DIM + 1];    // 2 KB wave-private h rows
    __shared__ int bfv;

    int t = threadIdx.x;
    if (t < 64) {   // dtype probe (proven)
        u32 wd = xw[t];
        u32 b = (wd >> 8) & 0x7fu;
        ull m2 = __ballot(b >= 0x38u && b <= 0x41u);
        if (t == 0) bfv = (__popcll(m2) >= 56) ? 1 : 0;
    }
    if (t < BK) hist[t] = 0;
    __syncthreads();
    int bf = bfv;
    int b = blockIdx.x, nb = b * BK;
    int m = qcnt[b]; if (m > QC) m = QC; if (m < 0) m = 0;
    const u32* q = qbuf + (size_t)b * QC;

    // stage self rows -> xs (f32), guarded for the partial last bucket
    if (bf) {
        const u32* xr = (const u32*)x + (size_t)nb * (IN_DIM / 2);
        int lim = ((N_NODES - nb < BK) ? (N_NODES - nb) : BK) * (IN_DIM / 2);
        for (int i = t; i < BK * (IN_DIM / 2); i += 256) {
            u32 w = (i < lim) ? __builtin_nontemporal_load(&xr[i]) : 0u;
            int r = i >> 4, c = i & 15;
            xs[r][2 * c]     = bf2f((u16)w);
            xs[r][2 * c + 1] = bf2f((u16)(w >> 16));
        }
    } else {
        const float* xr = (const float*)x + (size_t)nb * IN_DIM;
        int lim = ((N_NODES - nb < BK) ? (N_NODES - nb) : BK) * IN_DIM;
        for (int i = t; i < BK * IN_DIM; i += 256)
            xs[i >> 5][i & 31] = (i < lim) ? __builtin_nontemporal_load(&xr[i]) : 0.0f;
    }

    // ---- counting sort: histogram -> 1-wave scan (64 bins) -> scatter ----
    for (int i = t; i < m; i += 256)
        atomicAdd(&hist[__builtin_nontemporal_load(&q[i]) & 63], 1);
    __syncthreads();
    if (t < 64) {
        int v = hist[t];
        int inc = v;
        #pragma unroll
        for (int o = 1; o < 64; o <<= 1) {
            int y = __shfl_up(inc, o, 64);
            if (t >= o) inc += y;
        }
        int ex = inc - v;
        pos[t] = ex; pcur[t] = ex;
    }
    __syncthreads();
    for (int i = t; i < m; i += 256) {            // scatter src into sorted lists
        u32 u = __builtin_nontemporal_load(&q[i]);
        int p = atomicAdd(&pcur[u & 63], 1);
        srt[p] = u >> 6;
    }
    __syncthreads();

    // ---- half-dim gather passes (per-node rows stay wave-private) ----
    int wid = t >> 6, lane = t & 63;               // wid 0..3
    int half = lane >> 5;                          // node within pair
    int g3 = (lane >> 2) & 7;                      // 8 neighbor groups
    int l2 = lane & 3;                             // 8B chunk within half-row
    #pragma unroll
    for (int pass = 0; pass < 2; pass++) {
        const void* xh = pass ? xhi : xlo;
        int kb = pass * 16 + l2 * 4;               // dim base this lane covers
        for (int pr = 0; pr < 8; pr++) {
            int ns = pr * 8 + wid * 2 + half;
            int st = pos[ns], deg = hist[ns];
            float a0 = 0, a1 = 0, a2 = 0, a3 = 0;
            float c0 = 0, c1 = 0, c2 = 0, c3 = 0;
            int j = g3;
            for (; j + 24 < deg; j += 32) {        // ILP-4
                int sA = (int)srt[st + j];
                int sB = (int)srt[st + j + 8];
                int sC = (int)srt[st + j + 16];
                int sD = (int)srt[st + j + 24];
                if (bf) {
                    ushort4 vA = reinterpret_cast<const ushort4*>((const u16*)xh + (size_t)sA * 16)[l2];
                    ushort4 vB = reinterpret_cast<const ushort4*>((const u16*)xh + (size_t)sB * 16)[l2];
                    ushort4 vC = reinterpret_cast<const ushort4*>((const u16*)xh + (size_t)sC * 16)[l2];
                    ushort4 vD = reinterpret_cast<const ushort4*>((const u16*)xh + (size_t)sD * 16)[l2];
                    a0 += bf2f(vA.x); a1 += bf2f(vA.y); a2 += bf2f(vA.z); a3 += bf2f(vA.w);
                    c0 += bf2f(vB.x); c1 += bf2f(vB.y); c2 += bf2f(vB.z); c3 += bf2f(vB.w);
                    a0 += bf2f(vC.x); a1 += bf2f(vC.y); a2 += bf2f(vC.z); a3 += bf2f(vC.w);
                    c0 += bf2f(vD.x); c1 += bf2f(vD.y); c2 += bf2f(vD.z); c3 += bf2f(vD.w);
                } else {
                    float4 vA = reinterpret_cast<const float4*>((const float*)xh + (size_t)sA * 16)[l2];
                    float4 vB = reinterpret_cast<const float4*>((const float*)xh + (size_t)sB * 16)[l2];
                    float4 vC = reinterpret_cast<const float4*>((const float*)xh + (size_t)sC * 16)[l2];
                    float4 vD = reinterpret_cast<const float4*>((const float*)xh + (size_t)sD * 16)[l2];
                    a0 += vA.x; a1 += vA.y; a2 += vA.z; a3 += vA.w;
                    c0 += vB.x; c1 += vB.y; c2 += vB.z; c3 += vB.w;
                    a0 += vC.x; a1 += vC.y; a2 += vC.z; a3 += vC.w;
                    c0 += vD.x; c1 += vD.y; c2 += vD.z; c3 += vD.w;
                }
            }
            for (; j + 8 < deg; j += 16) {         // 2-way remainder
                int sA = (int)srt[st + j];
                int sB = (int)srt[st + j + 8];
                if (bf) {
                    ushort4 vA = reinterpret_cast<const ushort4*>((const u16*)xh + (size_t)sA * 16)[l2];
                    ushort4 vB = reinterpret_cast<const ushort4*>((const u16*)xh + (size_t)sB * 16)[l2];
                    a0 += bf2f(vA.x); a1 += bf2f(vA.y); a2 += bf2f(vA.z); a3 += bf2f(vA.w);
                    c0 += bf2f(vB.x); c1 += bf2f(vB.y); c2 += bf2f(vB.z); c3 += bf2f(vB.w);
                } else {
                    float4 vA = reinterpret_cast<const float4*>((const float*)xh + (size_t)sA * 16)[l2];
                    float4 vB = reinterpret_cast<const float4*>((const float*)xh + (size_t)sB * 16)[l2];
                    a0 += vA.x; a1 += vA.y; a2 += vA.z; a3 += vA.w;
                    c0 += vB.x; c1 += vB.y; c2 += vB.z; c3 += vB.w;
                }
            }
            if (j < deg) {                          // tail (at most one per group)
                int s = (int)srt[st + j];
                if (bf) {
                    ushort4 vv = reinterpret_cast<const ushort4*>((const u16*)xh + (size_t)s * 16)[l2];
                    a0 += bf2f(vv.x); a1 += bf2f(vv.y); a2 += bf2f(vv.z); a3 += bf2f(vv.w);
                } else {
                    float4 vv = reinterpret_cast<const float4*>((const float*)xh + (size_t)s * 16)[l2];
                    a0 += vv.x; a1 += vv.y; a2 += vv.z; a3 += vv.w;
                }
            }
            a0 += c0; a1 += c1; a2 += c2; a3 += c3;
            // reduce over the 8 groups (lane bits 2..4)
            a0 += __shfl_xor(a0, 4, 64); a0 += __shfl_xor(a0, 8, 64); a0 += __shfl_xor(a0, 16, 64);
            a1 += __shfl_xor(a1, 4, 64); a1 += __shfl_xor(a1, 8, 64); a1 += __shfl_xor(a1, 16, 64);
            a2 += __shfl_xor(a2, 4, 64); a2 += __shfl_xor(a2, 8, 64); a2 += __shfl_xor(a2, 16, 64);
            a3 += __shfl_xor(a3, 4, 64); a3 += __shfl_xor(a3, 8, 64); a3 += __shfl_xor(a3, 16, 64);
            if (g3 == 0) {                          // wave-private rows: no barrier
                agg[ns][kb + 0] = a0; agg[ns][kb + 1] = a1;
                agg[ns][kb + 2] = a2; agg[ns][kb + 3] = a3;
            }
        }
    }

    // ---- dense layer 1 + proj (R5-proven), reading agg/xs from LDS ----
    int g2 = (lane >> 3) & 3, l = lane & 7;
    int o = lane;
    float bb = tb1[o];
    for (int pr = 0; pr < 8; pr++) {
        int s0 = pr * 8 + wid * 2;
        int ns = s0 + half;
        float rd0 = 1.0f / fmaxf((float)hist[s0], 1.0f);
        float rd1 = 1.0f / fmaxf((float)hist[s0 + 1], 1.0f);
        float acc0 = bb, acc1 = bb;
        #pragma unroll 8
        for (int k = 0; k < IN_DIM; k++) {
            float wl = tW1l[k * HID_DIM + o];
            float wr = tW1r[k * HID_DIM + o];
            acc0 += (agg[s0][k] * rd0) * wl + xs[s0][k] * wr;
            acc1 += (agg[s0 + 1][k] * rd1) * wl + xs[s0 + 1][k] * wr;
        }
        hb[wid * 2][o]     = fmaxf(acc0, 0.0f);   // wave-private rows
        hb[wid * 2 + 1][o] = fmaxf(acc1, 0.0f);
        int hs = wid * 2 + half;
        float ga = 0.0f, ra = 0.0f;
        #pragma unroll 4
        for (int mm = 0; mm < 16; mm++) {
            int k = g2 * 16 + mm;
            float hv = hb[hs][k];
            ga += hv * tW2l[k * OUT_DIM + l];
            ra += hv * tW2r[k * OUT_DIM + l];
        }
        ga += __shfl_xor(ga, 8, 64);  ga += __shfl_xor(ga, 16, 64);
        ra += __shfl_xor(ra, 8, 64);  ra += __shfl_xor(ra, 16, 64);
        int n = nb + ns;
        if (g2 == 0 && n < N_NODES) {
            __builtin_nontemporal_store(f2bf(ga), &gbuf[(size_t)n * OUT_DIM + l]);
            __builtin_nontemporal_store(ra + tb2[l], &rbuf[(size_t)n * OUT_DIM + l]);
        }
    }
}

// ---- Layer 2 (R8-proven, + nt queue reads): counting sort, then gather
//      g[src] rows (L2-resident 1.6MB) with the 8-lane/node 4-way-ILP loop. ----
__global__ __launch_bounds__(256) void k_l2(
    const u16* __restrict__ gbuf, const float* __restrict__ rbuf,
    const int* __restrict__ qcnt, const u32* __restrict__ qbuf,
    const u32* __restrict__ xw, void* __restrict__ out)
{
    __shared__ int hist[BK], pos[BK], pcur[BK];
    __shared__ u32 srt[QC];
    __shared__ int bfv;
    int t = threadIdx.x;
    if (t < 64) {   // output-dtype probe (proven)
        u32 w = xw[t];
        u32 b = (w >> 8) & 0x7fu;
        ull m2 = __ballot(b >= 0x38u && b <= 0x41u);
        if (t == 0) bfv = (__popcll(m2) >= 56) ? 1 : 0;
    }
    if (t < BK) hist[t] = 0;
    __syncthreads();
    int b = blockIdx.x, nb = b * BK;
    int m = qcnt[b]; if (m > QC) m = QC; if (m < 0) m = 0;
    const u32* q = qbuf + (size_t)b * QC;

    for (int i = t; i < m; i += 256)
        atomicAdd(&hist[__builtin_nontemporal_load(&q[i]) & 63], 1);
    __syncthreads();
    if (t < 64) {
        int v = hist[t];
        int inc = v;
        #pragma unroll
        for (int o = 1; o < 64; o <<= 1) {
            int y = __shfl_up(inc, o, 64);
            if (t >= o) inc += y;
        }
        int ex = inc - v;
        pos[t] = ex; pcur[t] = ex;
    }
    __syncthreads();
    for (int i = t; i < m; i += 256) {
        u32 u = __builtin_nontemporal_load(&q[i]);
        int p = atomicAdd(&pcur[u & 63], 1);
        srt[p] = u >> 6;
    }
    __syncthreads();

    int grp = t >> 3, l = t & 7;          // 32 groups x 8 lanes
    for (int r = 0; r < 2; r++) {
        int ns = grp * 2 + r;             // node slot 0..63
        int st = pos[ns], deg = hist[ns];
        float a0 = 0.0f, a1 = 0.0f, a2 = 0.0f, a3 = 0.0f;
        int j = 0;
        for (; j + 3 < deg; j += 4) {
            int v0 = (int)srt[st + j];
            int v1 = (int)srt[st + j + 1];
            int v2 = (int)srt[st + j + 2];
            int v3 = (int)srt[st + j + 3];
            a0 += bf2f(gbuf[(size_t)v0 * OUT_DIM + l]);
            a1 += bf2f(gbuf[(size_t)v1 * OUT_DIM + l]);
            a2 += bf2f(gbuf[(size_t)v2 * OUT_DIM + l]);
            a3 += bf2f(gbuf[(size_t)v3 * OUT_DIM + l]);
        }
        for (; j < deg; j++) a0 += bf2f(gbuf[(size_t)srt[st + j] * OUT_DIM + l]);
        int n = nb + ns;
        if (n < N_NODES) {
            float res = (a0 + a1 + a2 + a3) / fmaxf((float)deg, 1.0f)
                      + rbuf[(size_t)n * OUT_DIM + l];
            size_t oi = (size_t)n * OUT_DIM + l;
            if (bfv) ((u16*)out)[oi] = f2bf(res);
            else     ((float*)out)[oi] = res;
        }
    }
}

extern "C" void kernel_launch(void* const* d_in, const int* in_sizes, int n_in,
                              void* d_out, int out_size, void* d_ws, size_t ws_size,
                              hipStream_t stream) {
    const void* x   = d_in[0];
    const int*  ei  = (const int*)d_in[1];
    const void* W1l = d_in[2];
    const void* b1  = d_in[3];
    const void* W1r = d_in[4];
    const void* W2l = d_in[5];
    const void* b2  = d_in[6];
    const void* W2r = d_in[7];

    // ws layout (4B units); total ~38.6 MB (ws >= 64.4 MB proven earlier)
    int* qcnt    = (int*)d_ws;                       // 2048 (memset, 1563 used)
    float* tW1l  = (float*)(qcnt + 2048);            // 2048
    float* tW1r  = tW1l + IN_DIM * HID_DIM;          // 2048
    float* tW2l  = tW1r + IN_DIM * HID_DIM;          // 512
    float* tW2r  = tW2l + HID_DIM * OUT_DIM;         // 512
    float* tb1   = tW2r + HID_DIM * OUT_DIM;         // 64
    float* tb2   = tb1 + HID_DIM;                    // 8
    u32* qbuf    = (u32*)(tb2 + OUT_DIM);            // NBKT*QC (8.0 MB, 16B-aligned)
    u16* gbuf    = (u16*)(qbuf + (size_t)NBKT * QC);           // N*8 u16 (1.6 MB)
    float* rbuf  = (float*)(gbuf + (size_t)N_NODES * OUT_DIM); // N*8 f32 (3.2 MB)
    u32* xlo     = (u32*)(rbuf + (size_t)N_NODES * OUT_DIM);   // N*16 u32 max (6.4 MB)
    u32* xhi     = xlo + (size_t)N_NODES * 16;                 // N*16 u32 max (6.4 MB)

    // zero qcnt only (8 KB)
    hipMemsetAsync(d_ws, 0, 2048 * sizeof(int), stream);

    k_part2<<<NCHUNK, 256, 0, stream>>>(ei, (const u32*)x,
                                        W1l, b1, W1r, W2l, b2, W2r,
                                        qcnt, qbuf,
                                        tW1l, tW1r, tW2l, tW2r, tb1, tb2,
                                        xlo, xhi);
    k_l1<<<NBKT, 256, 0, stream>>>(xlo, xhi, x, qcnt, qbuf,
                                   tW1l, tW1r, tW2l, tW2r, tb1, tb2,
                                   gbuf, rbuf, (const u32*)x);
    k_l2<<<NBKT, 256, 0, stream>>>(gbuf, rbuf, qcnt, qbuf,
                                   (const u32*)x, d_out);
}

// Round 10
// 222.897 us; speedup vs baseline: 1.0648x; 1.0648x over previous
//
#include <hip/hip_runtime.h>

#define N_NODES 100000
#define N_EDGES 1600000
#define IN_DIM 32
#define HID_DIM 64
#define OUT_DIM 8
#define BK 64                         // dst nodes per bucket
#define NBKT ((N_NODES + BK - 1) / BK)    // 1563
#define QC 1280                       // per-bucket queue cap (mean 1024, +8 sigma)
#define CHUNK 4096                    // edges per k_part2 block
#define NCHUNK ((N_EDGES + CHUNK - 1) / CHUNK)   // 391
#define SRC_MID 50000                 // src-half split for L2 phasing

typedef unsigned short u16;
typedef unsigned int u32;
typedef unsigned long long ull;

__device__ __forceinline__ float bf2f(u16 v) {
    return __uint_as_float(((u32)v) << 16);
}

__device__ __forceinline__ u16 f2bf(float f) {
    u32 u = __float_as_uint(f);
    u32 lsb = (u >> 16) & 1u;
    u += 0x7fffu + lsb;
    return (u16)(u >> 16);
}

__device__ __forceinline__ float ldf(const void* p, size_t i, int bf) {
    return bf ? bf2f(((const u16*)p)[i]) : ((const float*)p)[i];
}

// ---- Phase A (R8-proven, verbatim): dtype probe + weight transpose +
//      single-pass partition into 1563 dst-buckets of 64 nodes. ----
__global__ __launch_bounds__(256) void k_part2(
    const int* __restrict__ ei, const u32* __restrict__ xw,
    const void* __restrict__ W1l, const void* __restrict__ b1,
    const void* __restrict__ W1r,
    const void* __restrict__ W2l, const void* __restrict__ b2,
    const void* __restrict__ W2r,
    int* __restrict__ qcnt, u32* __restrict__ qbuf,
    float* __restrict__ tW1l, float* __restrict__ tW1r,
    float* __restrict__ tW2l, float* __restrict__ tW2r,
    float* __restrict__ tb1, float* __restrict__ tb2)
{
    __shared__ int shv, bfv;
    __shared__ int hist[NBKT], gbase[NBKT], lcur[NBKT];   // 18.8 KB
    int t = threadIdx.x;
    if (t < 64) {   // proven dtype probe, executed per block (same data)
        int v = ei[2 * t + 1];
        ull m1 = __ballot(v == 0);
        u32 wd = xw[t];
        u32 b = (wd >> 8) & 0x7fu;
        ull m2 = __ballot(b >= 0x38u && b <= 0x41u);
        if (t == 0) {
            shv = (m1 == ~0ULL) ? 1 : 0;
            bfv = (__popcll(m2) >= 56) ? 1 : 0;
        }
    }
    for (int i = t; i < NBKT; i += 256) { hist[i] = 0; lcur[i] = 0; }
    __syncthreads();
    int sh = shv, bf = bfv;

    if (blockIdx.x < 16) {        // weight transpose duty (R11-proven indexing)
        for (int i = blockIdx.x * 256 + t; i < HID_DIM * IN_DIM; i += 16 * 256) {
            int o = i / IN_DIM, k = i % IN_DIM;
            tW1l[k * HID_DIM + o] = ldf(W1l, i, bf);
            tW1r[k * HID_DIM + o] = ldf(W1r, i, bf);
        }
        for (int i = blockIdx.x * 256 + t; i < OUT_DIM * HID_DIM; i += 16 * 256) {
            int o = i / HID_DIM, k = i % HID_DIM;
            tW2l[k * OUT_DIM + o] = ldf(W2l, i, bf);
            tW2r[k * OUT_DIM + o] = ldf(W2r, i, bf);
        }
        if (blockIdx.x == 0) {
            if (t < HID_DIM) tb1[t] = ldf(b1, t, bf);
            if (t < OUT_DIM) tb2[t] = ldf(b2, t, bf);
        }
    }

    // edge partition (register-staged, R10-proven shape)
    int e0 = blockIdx.x * CHUNK;
    int myd[16], mys[16];
    #pragma unroll
    for (int i = 0; i < 16; i++) {
        int e = e0 + i * 256 + t;
        if (e < N_EDGES) {
            size_t off = (size_t)e << sh;
            mys[i] = ei[off];
            int d = ei[((size_t)N_EDGES << sh) + off];
            myd[i] = d;
            atomicAdd(&hist[d >> 6], 1);
        } else myd[i] = -1;
    }
    __syncthreads();
    for (int i = t; i < NBKT; i += 256) {
        int h = hist[i];
        gbase[i] = h ? atomicAdd(&qcnt[i], h) : 0;
    }
    __syncthreads();
    #pragma unroll
    for (int i = 0; i < 16; i++) {
        int d = myd[i];
        if (d >= 0) {
            int bk = d >> 6;
            int p = gbase[bk] + atomicAdd(&lcur[bk], 1);
            if (p < QC)
                qbuf[(size_t)bk * QC + p] = ((u32)mys[i] << 6) | (u32)(d & 63);
        }
    }
}

// ---- Layer 1: one 64-node bucket per block (R8-proven shell + gather).
//      NEW (R10): counting sort keys on (src-half, dst) -> 128 bins; the
//      ILP-4 gather runs as TWO TEMPORAL PASSES, pass 0 touching only
//      x rows with src<50000 (3.2MB bf16 -> fits per-XCD L2), pass 1 the
//      rest. Grid is fully resident (1563 blk ~ 6/CU) so all blocks phase
//      together -> per-phase union working set ~3.2MB. Rows stay 64B
//      (R9 lesson: 32B granules doubled FETCH). Partial sums carried in
//      LDS agg[64][32] (pass0 write, pass1 add; wave-private rows). ----
__global__ __launch_bounds__(256, 4) void k_l1(
    const void* __restrict__ x,
    const int* __restrict__ qcnt, const u32* __restrict__ qbuf,
    const float* __restrict__ tW1l, const float* __restrict__ tW1r,
    const float* __restrict__ tW2l, const float* __restrict__ tW2r,
    const float* __restrict__ tb1, const float* __restrict__ tb2,
    u16* __restrict__ gbuf, float* __restrict__ rbuf,
    const u32* __restrict__ xw)
{
    __shared__ int hist[2 * BK], pos[2 * BK], pcur[2 * BK];  // 1.5 KB
    __shared__ u32 srt[QC];                 // 5.1 KB sorted src lists
    __shared__ float xs[BK][IN_DIM];        // 8 KB self rows (f32)
    __shared__ float agg[BK][IN_DIM];       // 8 KB neighbor sums (f32)
    __shared__ float hb[8][HID_DIM + 1];    // 2 KB wave-private h rows
    __shared__ int wtot, bfv;

    int t = threadIdx.x;
    if (t < 64) {   // dtype probe (proven)
        u32 wd = xw[t];
        u32 b = (wd >> 8) & 0x7fu;
        ull m2 = __ballot(b >= 0x38u && b <= 0x41u);
        if (t == 0) bfv = (__popcll(m2) >= 56) ? 1 : 0;
    }
    if (t < 2 * BK) hist[t] = 0;
    __syncthreads();
    int bf = bfv;
    int b = blockIdx.x, nb = b * BK;
    int m = qcnt[b]; if (m > QC) m = QC; if (m < 0) m = 0;
    const u32* q = qbuf + (size_t)b * QC;

    // stage self rows -> xs (f32), guarded for the partial last bucket
    if (bf) {
        const u32* xr = (const u32*)x + (size_t)nb * (IN_DIM / 2);
        int lim = ((N_NODES - nb < BK) ? (N_NODES - nb) : BK) * (IN_DIM / 2);
        for (int i = t; i < BK * (IN_DIM / 2); i += 256) {
            u32 w = (i < lim) ? xr[i] : 0u;
            int r = i >> 4, c = i & 15;
            xs[r][2 * c]     = bf2f((u16)w);
            xs[r][2 * c + 1] = bf2f((u16)(w >> 16));
        }
    } else {
        const float* xr = (const float*)x + (size_t)nb * IN_DIM;
        int lim = ((N_NODES - nb < BK) ? (N_NODES - nb) : BK) * IN_DIM;
        for (int i = t; i < BK * IN_DIM; i += 256)
            xs[i >> 5][i & 31] = (i < lim) ? xr[i] : 0.0f;
    }

    // ---- counting sort: 128 bins (src-half * 64 + dst6) ----
    for (int i = t; i < m; i += 256) {
        u32 u = q[i];
        int bin = (((int)(u >> 6) >= SRC_MID) ? BK : 0) | (int)(u & 63);
        atomicAdd(&hist[bin], 1);
    }
    __syncthreads();
    int inc = 0, v = 0;
    if (t < 128) {                                 // 2-wave scan (R5-proven)
        v = hist[t]; inc = v;
        #pragma unroll
        for (int o = 1; o < 64; o <<= 1) {
            int y = __shfl_up(inc, o, 64);
            if ((t & 63) >= o) inc += y;
        }
        if (t == 63) wtot = inc;
    }
    __syncthreads();
    if (t < 128) {
        int ex = ((t >= 64) ? wtot : 0) + inc - v;
        pos[t] = ex; pcur[t] = ex;
    }
    __syncthreads();
    for (int i = t; i < m; i += 256) {            // scatter src into sorted lists
        u32 u = q[i];                             // L2-hot second pass
        int s = (int)(u >> 6);
        int bin = ((s >= SRC_MID) ? BK : 0) | (int)(u & 63);
        int p = atomicAdd(&pcur[bin], 1);
        srt[p] = (u32)s;
    }
    __syncthreads();

    // ---- two-pass gather (R8-proven inner loop, src-half phased) ----
    int wid = t >> 6, lane = t & 63;               // wid 0..3
    int half = lane >> 5, g2 = (lane >> 3) & 3, l = lane & 7;
    for (int pass = 0; pass < 2; pass++) {
        for (int pr = 0; pr < 8; pr++) {
            int ns = pr * 8 + wid * 2 + half;
            int bin = pass * BK + ns;
            int st = pos[bin], dg = hist[bin];
            float a0 = 0, a1 = 0, a2 = 0, a3 = 0;
            float c0 = 0, c1 = 0, c2 = 0, c3 = 0;
            float d0 = 0, d1 = 0, d2 = 0, d3 = 0;
            float e0 = 0, e1 = 0, e2 = 0, e3 = 0;
            int j = g2;
            for (; j + 12 < dg; j += 16) {   // 4 independent neighbor loads
                int sA = (int)srt[st + j];
                int sB = (int)srt[st + j + 4];
                int sC = (int)srt[st + j + 8];
                int sD = (int)srt[st + j + 12];
                if (bf) {
                    ushort4 vA = reinterpret_cast<const ushort4*>((const u16*)x + (size_t)sA * IN_DIM)[l];
                    ushort4 vB = reinterpret_cast<const ushort4*>((const u16*)x + (size_t)sB * IN_DIM)[l];
                    ushort4 vC = reinterpret_cast<const ushort4*>((const u16*)x + (size_t)sC * IN_DIM)[l];
                    ushort4 vD = reinterpret_cast<const ushort4*>((const u16*)x + (size_t)sD * IN_DIM)[l];
                    a0 += bf2f(vA.x); a1 += bf2f(vA.y); a2 += bf2f(vA.z); a3 += bf2f(vA.w);
                    c0 += bf2f(vB.x); c1 += bf2f(vB.y); c2 += bf2f(vB.z); c3 += bf2f(vB.w);
                    d0 += bf2f(vC.x); d1 += bf2f(vC.y); d2 += bf2f(vC.z); d3 += bf2f(vC.w);
                    e0 += bf2f(vD.x); e1 += bf2f(vD.y); e2 += bf2f(vD.z); e3 += bf2f(vD.w);
                } else {
                    float4 vA = reinterpret_cast<const float4*>((const float*)x + (size_t)sA * IN_DIM)[l];
                    float4 vB = reinterpret_cast<const float4*>((const float*)x + (size_t)sB * IN_DIM)[l];
                    float4 vC = reinterpret_cast<const float4*>((const float*)x + (size_t)sC * IN_DIM)[l];
                    float4 vD = reinterpret_cast<const float4*>((const float*)x + (size_t)sD * IN_DIM)[l];
                    a0 += vA.x; a1 += vA.y; a2 += vA.z; a3 += vA.w;
                    c0 += vB.x; c1 += vB.y; c2 += vB.z; c3 += vB.w;
                    d0 += vC.x; d1 += vC.y; d2 += vC.z; d3 += vC.w;
                    e0 += vD.x; e1 += vD.y; e2 += vD.z; e3 += vD.w;
                }
            }
            for (; j + 4 < dg; j += 8) {     // 2-way remainder
                int sA = (int)srt[st + j];
                int sB = (int)srt[st + j + 4];
                if (bf) {
                    ushort4 vA = reinterpret_cast<const ushort4*>((const u16*)x + (size_t)sA * IN_DIM)[l];
                    ushort4 vB = reinterpret_cast<const ushort4*>((const u16*)x + (size_t)sB * IN_DIM)[l];
                    a0 += bf2f(vA.x); a1 += bf2f(vA.y); a2 += bf2f(vA.z); a3 += bf2f(vA.w);
                    c0 += bf2f(vB.x); c1 += bf2f(vB.y); c2 += bf2f(vB.z); c3 += bf2f(vB.w);
                } else {
                    float4 vA = reinterpret_cast<const float4*>((const float*)x + (size_t)sA * IN_DIM)[l];
                    float4 vB = reinterpret_cast<const float4*>((const float*)x + (size_t)sB * IN_DIM)[l];
                    a0 += vA.x; a1 += vA.y; a2 += vA.z; a3 += vA.w;
                    c0 += vB.x; c1 += vB.y; c2 += vB.z; c3 += vB.w;
                }
            }
            if (j < dg) {                    // tail (at most one per group)
                int s = (int)srt[st + j];
                if (bf) {
                    ushort4 vv = reinterpret_cast<const ushort4*>((const u16*)x + (size_t)s * IN_DIM)[l];
                    a0 += bf2f(vv.x); a1 += bf2f(vv.y); a2 += bf2f(vv.z); a3 += bf2f(vv.w);
                } else {
                    float4 vv = reinterpret_cast<const float4*>((const float*)x + (size_t)s * IN_DIM)[l];
                    a0 += vv.x; a1 += vv.y; a2 += vv.z; a3 += vv.w;
                }
            }
            a0 += c0 + d0 + e0;
            a1 += c1 + d1 + e1;
            a2 += c2 + d2 + e2;
            a3 += c3 + d3 + e3;
            a0 += __shfl_xor(a0, 8, 64);  a0 += __shfl_xor(a0, 16, 64);
            a1 += __shfl_xor(a1, 8, 64);  a1 += __shfl_xor(a1, 16, 64);
            a2 += __shfl_xor(a2, 8, 64);  a2 += __shfl_xor(a2, 16, 64);
            a3 += __shfl_xor(a3, 8, 64);  a3 += __shfl_xor(a3, 16, 64);
            if (g2 == 0) {                   // wave-private row: no barrier
                float* ar = &agg[ns][4 * l];
                if (pass == 0) { ar[0] = a0; ar[1] = a1; ar[2] = a2; ar[3] = a3; }
                else           { ar[0] += a0; ar[1] += a1; ar[2] += a2; ar[3] += a3; }
            }
        }
    }

    // ---- dense layer 1 + proj (R5-proven), agg/xs from LDS ----
    int o = lane;
    float bb = tb1[o];
    for (int pr = 0; pr < 8; pr++) {
        int s0 = pr * 8 + wid * 2;
        int ns = s0 + half;
        float rd0 = 1.0f / fmaxf((float)(hist[s0] + hist[BK + s0]), 1.0f);
        float rd1 = 1.0f / fmaxf((float)(hist[s0 + 1] + hist[BK + s0 + 1]), 1.0f);
        float acc0 = bb, acc1 = bb;
        #pragma unroll 8
        for (int k = 0; k < IN_DIM; k++) {
            float wl = tW1l[k * HID_DIM + o];
            float wr = tW1r[k * HID_DIM + o];
            acc0 += (agg[s0][k] * rd0) * wl + xs[s0][k] * wr;
            acc1 += (agg[s0 + 1][k] * rd1) * wl + xs[s0 + 1][k] * wr;
        }
        hb[wid * 2][o]     = fmaxf(acc0, 0.0f);   // wave-private rows
        hb[wid * 2 + 1][o] = fmaxf(acc1, 0.0f);
        int hs = wid * 2 + half;
        float ga = 0.0f, ra = 0.0f;
        #pragma unroll 4
        for (int mm = 0; mm < 16; mm++) {
            int k = g2 * 16 + mm;
            float hv = hb[hs][k];
            ga += hv * tW2l[k * OUT_DIM + l];
            ra += hv * tW2r[k * OUT_DIM + l];
        }
        ga += __shfl_xor(ga, 8, 64);  ga += __shfl_xor(ga, 16, 64);
        ra += __shfl_xor(ra, 8, 64);  ra += __shfl_xor(ra, 16, 64);
        int n = nb + ns;
        if (g2 == 0 && n < N_NODES) {
            __builtin_nontemporal_store(f2bf(ga), &gbuf[(size_t)n * OUT_DIM + l]);
            __builtin_nontemporal_store(ra + tb2[l], &rbuf[(size_t)n * OUT_DIM + l]);
        }
    }
}

// ---- Layer 2 (R8-proven, verbatim): counting sort, then gather g[src]
//      rows (L2-resident 1.6MB) with the 8-lane/node 4-way-ILP loop. ----
__global__ __launch_bounds__(256) void k_l2(
    const u16* __restrict__ gbuf, const float* __restrict__ rbuf,
    const int* __restrict__ qcnt, const u32* __restrict__ qbuf,
    const u32* __restrict__ xw, void* __restrict__ out)
{
    __shared__ int hist[BK], pos[BK], pcur[BK];
    __shared__ u32 srt[QC];
    __shared__ int bfv;
    int t = threadIdx.x;
    if (t < 64) {   // output-dtype probe (proven)
        u32 w = xw[t];
        u32 b = (w >> 8) & 0x7fu;
        ull m2 = __ballot(b >= 0x38u && b <= 0x41u);
        if (t == 0) bfv = (__popcll(m2) >= 56) ? 1 : 0;
    }
    if (t < BK) hist[t] = 0;
    __syncthreads();
    int b = blockIdx.x, nb = b * BK;
    int m = qcnt[b]; if (m > QC) m = QC; if (m < 0) m = 0;
    const u32* q = qbuf + (size_t)b * QC;

    for (int i = t; i < m; i += 256)
        atomicAdd(&hist[q[i] & 63], 1);
    __syncthreads();
    if (t < 64) {
        int v = hist[t];
        int inc = v;
        #pragma unroll
        for (int o = 1; o < 64; o <<= 1) {
            int y = __shfl_up(inc, o, 64);
            if (t >= o) inc += y;
        }
        int ex = inc - v;
        pos[t] = ex; pcur[t] = ex;
    }
    __syncthreads();
    for (int i = t; i < m; i += 256) {
        u32 u = q[i];
        int p = atomicAdd(&pcur[u & 63], 1);
        srt[p] = u >> 6;
    }
    __syncthreads();

    int grp = t >> 3, l = t & 7;          // 32 groups x 8 lanes
    for (int r = 0; r < 2; r++) {
        int ns = grp * 2 + r;             // node slot 0..63
        int st = pos[ns], deg = hist[ns];
        float a0 = 0.0f, a1 = 0.0f, a2 = 0.0f, a3 = 0.0f;
        int j = 0;
        for (; j + 3 < deg; j += 4) {
            int v0 = (int)srt[st + j];
            int v1 = (int)srt[st + j + 1];
            int v2 = (int)srt[st + j + 2];
            int v3 = (int)srt[st + j + 3];
            a0 += bf2f(gbuf[(size_t)v0 * OUT_DIM + l]);
            a1 += bf2f(gbuf[(size_t)v1 * OUT_DIM + l]);
            a2 += bf2f(gbuf[(size_t)v2 * OUT_DIM + l]);
            a3 += bf2f(gbuf[(size_t)v3 * OUT_DIM + l]);
        }
        for (; j < deg; j++) a0 += bf2f(gbuf[(size_t)srt[st + j] * OUT_DIM + l]);
        int n = nb + ns;
        if (n < N_NODES) {
            float res = (a0 + a1 + a2 + a3) / fmaxf((float)deg, 1.0f)
                      + rbuf[(size_t)n * OUT_DIM + l];
            size_t oi = (size_t)n * OUT_DIM + l;
            if (bfv) ((u16*)out)[oi] = f2bf(res);
            else     ((float*)out)[oi] = res;
        }
    }
}

extern "C" void kernel_launch(void* const* d_in, const int* in_sizes, int n_in,
                              void* d_out, int out_size, void* d_ws, size_t ws_size,
                              hipStream_t stream) {
    const void* x   = d_in[0];
    const int*  ei  = (const int*)d_in[1];
    const void* W1l = d_in[2];
    const void* b1  = d_in[3];
    const void* W1r = d_in[4];
    const void* W2l = d_in[5];
    const void* b2  = d_in[6];
    const void* W2r = d_in[7];

    // ws layout (4B units); total ~13 MB (ws >= 64.4 MB proven earlier)
    int* qcnt    = (int*)d_ws;                       // 2048 (memset, 1563 used)
    float* tW1l  = (float*)(qcnt + 2048);            // 2048
    float* tW1r  = tW1l + IN_DIM * HID_DIM;          // 2048
    float* tW2l  = tW1r + IN_DIM * HID_DIM;          // 512
    float* tW2r  = tW2l + HID_DIM * OUT_DIM;         // 512
    float* tb1   = tW2r + HID_DIM * OUT_DIM;         // 64
    float* tb2   = tb1 + HID_DIM;                    // 8
    u32* qbuf    = (u32*)(tb2 + OUT_DIM);            // NBKT*QC (8.0 MB, 16B-aligned)
    u16* gbuf    = (u16*)(qbuf + (size_t)NBKT * QC);           // N*8 u16 (1.6 MB)
    float* rbuf  = (float*)(gbuf + (size_t)N_NODES * OUT_DIM); // N*8 f32 (3.2 MB)

    // zero qcnt only (8 KB)
    hipMemsetAsync(d_ws, 0, 2048 * sizeof(int), stream);

    k_part2<<<NCHUNK, 256, 0, stream>>>(ei, (const u32*)x,
                                        W1l, b1, W1r, W2l, b2, W2r,
                                        qcnt, qbuf,
                                        tW1l, tW1r, tW2l, tW2r, tb1, tb2);
    k_l1<<<NBKT, 256, 0, stream>>>(x, qcnt, qbuf,
                                   tW1l, tW1r, tW2l, tW2r, tb1, tb2,
                                   gbuf, rbuf, (const u32*)x);
    k_l2<<<NBKT, 256, 0, stream>>>(gbuf, rbuf, qcnt, qbuf,
                                   (const u32*)x, d_out);
}

// Round 11
// 213.455 us; speedup vs baseline: 1.1119x; 1.0442x over previous
//
#include <hip/hip_runtime.h>

#define N_NODES 100000
#define N_EDGES 1600000
#define IN_DIM 32
#define HID_DIM 64
#define OUT_DIM 8
#define BK 64                         // dst nodes per bucket
#define NBKT ((N_NODES + BK - 1) / BK)    // 1563
#define QC 1280                       // per-bucket total cap (mean 1024, +8 sigma)
#define QCP 224                       // per-(bucket,XCD-partition) cap (mean 128, +8.5 sigma)
#define QSTR 2048                     // qcnt partition stride
#define CHUNK 4096                    // edges per k_part2 block
#define NCHUNK ((N_EDGES + CHUNK - 1) / CHUNK)   // 391

typedef unsigned short u16;
typedef unsigned int u32;
typedef unsigned long long ull;

__device__ __forceinline__ float bf2f(u16 v) {
    return __uint_as_float(((u32)v) << 16);
}

__device__ __forceinline__ u16 f2bf(float f) {
    u32 u = __float_as_uint(f);
    u32 lsb = (u >> 16) & 1u;
    u += 0x7fffu + lsb;
    return (u16)(u >> 16);
}

__device__ __forceinline__ float ldf(const void* p, size_t i, int bf) {
    return bf ? bf2f(((const u16*)p)[i]) : ((const float*)p)[i];
}

// ---- Phase A: R8-proven partition, NOW XCD-PARTITIONED (R11): blocks
//      dispatch round-robin over 8 XCDs, so partition p = blockIdx&7 makes
//      every qbuf line written by ONE XCD -> dirty lines stay in that L2
//      (kills the cross-XCD 4B-store ping-pong measured in R1: 63.6MB
//      writes for 6.4MB useful). Cursor atomics become XCD-local too. ----
__global__ __launch_bounds__(256) void k_part2(
    const int* __restrict__ ei, const u32* __restrict__ xw,
    const void* __restrict__ W1l, const void* __restrict__ b1,
    const void* __restrict__ W1r,
    const void* __restrict__ W2l, const void* __restrict__ b2,
    const void* __restrict__ W2r,
    int* __restrict__ qcnt, u32* __restrict__ qbuf,
    float* __restrict__ tW1l, float* __restrict__ tW1r,
    float* __restrict__ tW2l, float* __restrict__ tW2r,
    float* __restrict__ tb1, float* __restrict__ tb2)
{
    __shared__ int shv, bfv;
    __shared__ int hist[NBKT], gbase[NBKT], lcur[NBKT];   // 18.8 KB
    int t = threadIdx.x;
    int part = blockIdx.x & 7;        // XCD proxy (round-robin dispatch)
    if (t < 64) {   // proven dtype probe, executed per block (same data)
        int v = ei[2 * t + 1];
        ull m1 = __ballot(v == 0);
        u32 wd = xw[t];
        u32 b = (wd >> 8) & 0x7fu;
        ull m2 = __ballot(b >= 0x38u && b <= 0x41u);
        if (t == 0) {
            shv = (m1 == ~0ULL) ? 1 : 0;
            bfv = (__popcll(m2) >= 56) ? 1 : 0;
        }
    }
    for (int i = t; i < NBKT; i += 256) { hist[i] = 0; lcur[i] = 0; }
    __syncthreads();
    int sh = shv, bf = bfv;

    if (blockIdx.x < 16) {        // weight transpose duty (R11-proven indexing)
        for (int i = blockIdx.x * 256 + t; i < HID_DIM * IN_DIM; i += 16 * 256) {
            int o = i / IN_DIM, k = i % IN_DIM;
            tW1l[k * HID_DIM + o] = ldf(W1l, i, bf);
            tW1r[k * HID_DIM + o] = ldf(W1r, i, bf);
        }
        for (int i = blockIdx.x * 256 + t; i < OUT_DIM * HID_DIM; i += 16 * 256) {
            int o = i / HID_DIM, k = i % HID_DIM;
            tW2l[k * OUT_DIM + o] = ldf(W2l, i, bf);
            tW2r[k * OUT_DIM + o] = ldf(W2r, i, bf);
        }
        if (blockIdx.x == 0) {
            if (t < HID_DIM) tb1[t] = ldf(b1, t, bf);
            if (t < OUT_DIM) tb2[t] = ldf(b2, t, bf);
        }
    }

    // edge partition (register-staged, R10-proven shape; nt ei reads keep
    // the stream from evicting this partition's dirty qbuf lines)
    int e0 = blockIdx.x * CHUNK;
    int myd[16], mys[16];
    #pragma unroll
    for (int i = 0; i < 16; i++) {
        int e = e0 + i * 256 + t;
        if (e < N_EDGES) {
            size_t off = (size_t)e << sh;
            mys[i] = __builtin_nontemporal_load(&ei[off]);
            int d = __builtin_nontemporal_load(&ei[((size_t)N_EDGES << sh) + off]);
            myd[i] = d;
            atomicAdd(&hist[d >> 6], 1);
        } else myd[i] = -1;
    }
    __syncthreads();
    for (int i = t; i < NBKT; i += 256) {
        int h = hist[i];
        gbase[i] = h ? atomicAdd(&qcnt[part * QSTR + i], h) : 0;
    }
    __syncthreads();
    #pragma unroll
    for (int i = 0; i < 16; i++) {
        int d = myd[i];
        if (d >= 0) {
            int bk = d >> 6;
            int p = gbase[bk] + atomicAdd(&lcur[bk], 1);
            if (p < QCP)
                qbuf[((size_t)part * NBKT + bk) * QCP + p] =
                    ((u32)mys[i] << 6) | (u32)(d & 63);
        }
    }
}

// ---- Layer 1 (R8-proven gather/dense, verbatim): one 64-node bucket per
//      block. NEW prologue: stage the 8 XCD-partition segments into LDS
//      raw[] (coalesced), then counting-sort raw->srt as before. ----
__global__ __launch_bounds__(256, 4) void k_l1(
    const void* __restrict__ x,
    const int* __restrict__ qcnt, const u32* __restrict__ qbuf,
    const float* __restrict__ tW1l, const float* __restrict__ tW1r,
    const float* __restrict__ tW2l, const float* __restrict__ tW2r,
    const float* __restrict__ tb1, const float* __restrict__ tb2,
    u16* __restrict__ gbuf, float* __restrict__ rbuf,
    const u32* __restrict__ xw)
{
    __shared__ int hist[BK], pos[BK], pcur[BK];   // 0.75 KB
    __shared__ int mp[8], mbase[8], mtv;
    __shared__ u32 raw[QC];                 // 5.1 KB staged queue entries
    __shared__ u32 srt[QC];                 // 5.1 KB sorted src lists
    __shared__ float xs[BK][IN_DIM];        // 8 KB self rows (f32)
    __shared__ float aggw[4][2][IN_DIM];    // 1 KB wave-private agg pair
    __shared__ float hb[8][HID_DIM + 1];    // 2 KB wave-private h rows
    __shared__ int bfv;

    int t = threadIdx.x;
    if (t < 64) {   // dtype probe (proven)
        u32 wd = xw[t];
        u32 b = (wd >> 8) & 0x7fu;
        ull m2 = __ballot(b >= 0x38u && b <= 0x41u);
        if (t == 0) bfv = (__popcll(m2) >= 56) ? 1 : 0;
    }
    if (t < BK) hist[t] = 0;
    int b = blockIdx.x, nb = b * BK;
    if (t < 8) {
        int v = qcnt[t * QSTR + b];
        if (v < 0) v = 0;
        if (v > QCP) v = QCP;
        mp[t] = v;
    }
    __syncthreads();
    int bf = bfv;
    if (t == 0) {       // sequential clamp so total fits srt/raw (QC)
        int s = 0;
        for (int p = 0; p < 8; p++) {
            mbase[p] = s;
            int v = mp[p];
            if (s + v > QC) v = QC - s;
            if (v < 0) v = 0;
            mp[p] = v; s += v;
        }
        mtv = s;
    }
    __syncthreads();
    int m = mtv;

    // stage the 8 partition segments into raw[] (coalesced reads)
    for (int p = 0; p < 8; p++) {
        const u32* qp = qbuf + ((size_t)p * NBKT + b) * QCP;
        int mpp = mp[p], mb = mbase[p];
        for (int i = t; i < mpp; i += 256)
            raw[mb + i] = __builtin_nontemporal_load(&qp[i]);
    }

    // stage self rows -> xs (f32), guarded for the partial last bucket
    if (bf) {
        const u32* xr = (const u32*)x + (size_t)nb * (IN_DIM / 2);
        int lim = ((N_NODES - nb < BK) ? (N_NODES - nb) : BK) * (IN_DIM / 2);
        for (int i = t; i < BK * (IN_DIM / 2); i += 256) {
            u32 w = (i < lim) ? xr[i] : 0u;
            int r = i >> 4, c = i & 15;
            xs[r][2 * c]     = bf2f((u16)w);
            xs[r][2 * c + 1] = bf2f((u16)(w >> 16));
        }
    } else {
        const float* xr = (const float*)x + (size_t)nb * IN_DIM;
        int lim = ((N_NODES - nb < BK) ? (N_NODES - nb) : BK) * IN_DIM;
        for (int i = t; i < BK * IN_DIM; i += 256)
            xs[i >> 5][i & 31] = (i < lim) ? xr[i] : 0.0f;
    }
    __syncthreads();

    // ---- counting sort (R8-proven): histogram -> 1-wave scan -> scatter ----
    for (int i = t; i < m; i += 256)
        atomicAdd(&hist[raw[i] & 63], 1);
    __syncthreads();
    if (t < 64) {
        int v = hist[t];
        int inc = v;
        #pragma unroll
        for (int o = 1; o < 64; o <<= 1) {
            int y = __shfl_up(inc, o, 64);
            if (t >= o) inc += y;
        }
        int ex = inc - v;
        pos[t] = ex; pcur[t] = ex;
    }
    __syncthreads();
    for (int i = t; i < m; i += 256) {
        u32 u = raw[i];
        int p = atomicAdd(&pcur[u & 63], 1);
        srt[p] = u >> 6;
    }
    __syncthreads();

    // ---- per-pair gather (R8-proven ILP-4 loop) + dense + proj ----
    int wid = t >> 6, lane = t & 63;               // wid 0..3
    int half = lane >> 5, g2 = (lane >> 3) & 3, l = lane & 7;
    int o = lane;
    float bb = tb1[o];
    for (int pr = 0; pr < 8; pr++) {
        int s0 = pr * 8 + wid * 2;
        int ns = s0 + half;
        int st = pos[ns], deg = hist[ns];
        float a0 = 0, a1 = 0, a2 = 0, a3 = 0;
        float c0 = 0, c1 = 0, c2 = 0, c3 = 0;
        float d0 = 0, d1 = 0, d2 = 0, d3 = 0;
        float e0 = 0, e1 = 0, e2 = 0, e3 = 0;
        int j = g2;
        for (; j + 12 < deg; j += 16) {   // 4 independent neighbor loads in flight
            int sA = (int)srt[st + j];
            int sB = (int)srt[st + j + 4];
            int sC = (int)srt[st + j + 8];
            int sD = (int)srt[st + j + 12];
            if (bf) {
                ushort4 vA = reinterpret_cast<const ushort4*>((const u16*)x + (size_t)sA * IN_DIM)[l];
                ushort4 vB = reinterpret_cast<const ushort4*>((const u16*)x + (size_t)sB * IN_DIM)[l];
                ushort4 vC = reinterpret_cast<const ushort4*>((const u16*)x + (size_t)sC * IN_DIM)[l];
                ushort4 vD = reinterpret_cast<const ushort4*>((const u16*)x + (size_t)sD * IN_DIM)[l];
                a0 += bf2f(vA.x); a1 += bf2f(vA.y); a2 += bf2f(vA.z); a3 += bf2f(vA.w);
                c0 += bf2f(vB.x); c1 += bf2f(vB.y); c2 += bf2f(vB.z); c3 += bf2f(vB.w);
                d0 += bf2f(vC.x); d1 += bf2f(vC.y); d2 += bf2f(vC.z); d3 += bf2f(vC.w);
                e0 += bf2f(vD.x); e1 += bf2f(vD.y); e2 += bf2f(vD.z); e3 += bf2f(vD.w);
            } else {
                float4 vA = reinterpret_cast<const float4*>((const float*)x + (size_t)sA * IN_DIM)[l];
                float4 vB = reinterpret_cast<const float4*>((const float*)x + (size_t)sB * IN_DIM)[l];
                float4 vC = reinterpret_cast<const float4*>((const float*)x + (size_t)sC * IN_DIM)[l];
                float4 vD = reinterpret_cast<const float4*>((const float*)x + (size_t)sD * IN_DIM)[l];
                a0 += vA.x; a1 += vA.y; a2 += vA.z; a3 += vA.w;
                c0 += vB.x; c1 += vB.y; c2 += vB.z; c3 += vB.w;
                d0 += vC.x; d1 += vC.y; d2 += vC.z; d3 += vC.w;
                e0 += vD.x; e1 += vD.y; e2 += vD.z; e3 += vD.w;
            }
        }
        for (; j + 4 < deg; j += 8) {     // 2-way remainder
            int sA = (int)srt[st + j];
            int sB = (int)srt[st + j + 4];
            if (bf) {
                ushort4 vA = reinterpret_cast<const ushort4*>((const u16*)x + (size_t)sA * IN_DIM)[l];
                ushort4 vB = reinterpret_cast<const ushort4*>((const u16*)x + (size_t)sB * IN_DIM)[l];
                a0 += bf2f(vA.x); a1 += bf2f(vA.y); a2 += bf2f(vA.z); a3 += bf2f(vA.w);
                c0 += bf2f(vB.x); c1 += bf2f(vB.y); c2 += bf2f(vB.z); c3 += bf2f(vB.w);
            } else {
                float4 vA = reinterpret_cast<const float4*>((const float*)x + (size_t)sA * IN_DIM)[l];
                float4 vB = reinterpret_cast<const float4*>((const float*)x + (size_t)sB * IN_DIM)[l];
                a0 += vA.x; a1 += vA.y; a2 += vA.z; a3 += vA.w;
                c0 += vB.x; c1 += vB.y; c2 += vB.z; c3 += vB.w;
            }
        }
        if (j < deg) {                    // tail (at most one per group)
            int s = (int)srt[st + j];
            if (bf) {
                ushort4 vv = reinterpret_cast<const ushort4*>((const u16*)x + (size_t)s * IN_DIM)[l];
                a0 += bf2f(vv.x); a1 += bf2f(vv.y); a2 += bf2f(vv.z); a3 += bf2f(vv.w);
            } else {
                float4 vv = reinterpret_cast<const float4*>((const float*)x + (size_t)s * IN_DIM)[l];
                a0 += vv.x; a1 += vv.y; a2 += vv.z; a3 += vv.w;
            }
        }
        a0 += c0 + d0 + e0;
        a1 += c1 + d1 + e1;
        a2 += c2 + d2 + e2;
        a3 += c3 + d3 + e3;
        a0 += __shfl_xor(a0, 8, 64);  a0 += __shfl_xor(a0, 16, 64);
        a1 += __shfl_xor(a1, 8, 64);  a1 += __shfl_xor(a1, 16, 64);
        a2 += __shfl_xor(a2, 8, 64);  a2 += __shfl_xor(a2, 16, 64);
        a3 += __shfl_xor(a3, 8, 64);  a3 += __shfl_xor(a3, 16, 64);
        if (g2 == 0) {                    // wave-private: no barrier needed
            aggw[wid][half][4 * l + 0] = a0; aggw[wid][half][4 * l + 1] = a1;
            aggw[wid][half][4 * l + 2] = a2; aggw[wid][half][4 * l + 3] = a3;
        }
        // dense layer 1 (each lane = output o, both nodes of the pair)
        float rd0 = 1.0f / fmaxf((float)hist[s0], 1.0f);
        float rd1 = 1.0f / fmaxf((float)hist[s0 + 1], 1.0f);
        float acc0 = bb, acc1 = bb;
        #pragma unroll 8
        for (int k = 0; k < IN_DIM; k++) {
            float wl = tW1l[k * HID_DIM + o];
            float wr = tW1r[k * HID_DIM + o];
            acc0 += (aggw[wid][0][k] * rd0) * wl + xs[s0][k] * wr;
            acc1 += (aggw[wid][1][k] * rd1) * wl + xs[s0 + 1][k] * wr;
        }
        hb[wid * 2][o]     = fmaxf(acc0, 0.0f);   // wave-private rows
        hb[wid * 2 + 1][o] = fmaxf(acc1, 0.0f);
        // layer-2 projections: g = h@W2l^T (bf16-packed), r = h@W2r^T + b2
        int hs = wid * 2 + half;
        float ga = 0.0f, ra = 0.0f;
        #pragma unroll 4
        for (int mm = 0; mm < 16; mm++) {
            int k = g2 * 16 + mm;
            float hv = hb[hs][k];
            ga += hv * tW2l[k * OUT_DIM + l];
            ra += hv * tW2r[k * OUT_DIM + l];
        }
        ga += __shfl_xor(ga, 8, 64);  ga += __shfl_xor(ga, 16, 64);
        ra += __shfl_xor(ra, 8, 64);  ra += __shfl_xor(ra, 16, 64);
        int n = nb + ns;
        if (g2 == 0 && n < N_NODES) {
            __builtin_nontemporal_store(f2bf(ga), &gbuf[(size_t)n * OUT_DIM + l]);
            __builtin_nontemporal_store(ra + tb2[l], &rbuf[(size_t)n * OUT_DIM + l]);
        }
    }
}

// ---- Layer 2 (R8-proven gather; same staged-raw prologue as k_l1). ----
__global__ __launch_bounds__(256) void k_l2(
    const u16* __restrict__ gbuf, const float* __restrict__ rbuf,
    const int* __restrict__ qcnt, const u32* __restrict__ qbuf,
    const u32* __restrict__ xw, void* __restrict__ out)
{
    __shared__ int hist[BK], pos[BK], pcur[BK];
    __shared__ int mp[8], mbase[8], mtv;
    __shared__ u32 raw[QC];
    __shared__ u32 srt[QC];
    __shared__ int bfv;
    int t = threadIdx.x;
    if (t < 64) {   // output-dtype probe (proven)
        u32 w = xw[t];
        u32 b = (w >> 8) & 0x7fu;
        ull m2 = __ballot(b >= 0x38u && b <= 0x41u);
        if (t == 0) bfv = (__popcll(m2) >= 56) ? 1 : 0;
    }
    if (t < BK) hist[t] = 0;
    int b = blockIdx.x, nb = b * BK;
    if (t < 8) {
        int v = qcnt[t * QSTR + b];
        if (v < 0) v = 0;
        if (v > QCP) v = QCP;
        mp[t] = v;
    }
    __syncthreads();
    if (t == 0) {
        int s = 0;
        for (int p = 0; p < 8; p++) {
            mbase[p] = s;
            int v = mp[p];
            if (s + v > QC) v = QC - s;
            if (v < 0) v = 0;
            mp[p] = v; s += v;
        }
        mtv = s;
    }
    __syncthreads();
    int m = mtv;
    for (int p = 0; p < 8; p++) {
        const u32* qp = qbuf + ((size_t)p * NBKT + b) * QCP;
        int mpp = mp[p], mb = mbase[p];
        for (int i = t; i < mpp; i += 256)
            raw[mb + i] = __builtin_nontemporal_load(&qp[i]);
    }
    __syncthreads();

    for (int i = t; i < m; i += 256)
        atomicAdd(&hist[raw[i] & 63], 1);
    __syncthreads();
    if (t < 64) {
        int v = hist[t];
        int inc = v;
        #pragma unroll
        for (int o = 1; o < 64; o <<= 1) {
            int y = __shfl_up(inc, o, 64);
            if (t >= o) inc += y;
        }
        int ex = inc - v;
        pos[t] = ex; pcur[t] = ex;
    }
    __syncthreads();
    for (int i = t; i < m; i += 256) {
        u32 u = raw[i];
        int p = atomicAdd(&pcur[u & 63], 1);
        srt[p] = u >> 6;
    }
    __syncthreads();

    int grp = t >> 3, l = t & 7;          // 32 groups x 8 lanes
    for (int r = 0; r < 2; r++) {
        int ns = grp * 2 + r;             // node slot 0..63
        int st = pos[ns], deg = hist[ns];
        float a0 = 0.0f, a1 = 0.0f, a2 = 0.0f, a3 = 0.0f;
        int j = 0;
        for (; j + 3 < deg; j += 4) {
            int v0 = (int)srt[st + j];
            int v1 = (int)srt[st + j + 1];
            int v2 = (int)srt[st + j + 2];
            int v3 = (int)srt[st + j + 3];
            a0 += bf2f(gbuf[(size_t)v0 * OUT_DIM + l]);
            a1 += bf2f(gbuf[(size_t)v1 * OUT_DIM + l]);
            a2 += bf2f(gbuf[(size_t)v2 * OUT_DIM + l]);
            a3 += bf2f(gbuf[(size_t)v3 * OUT_DIM + l]);
        }
        for (; j < deg; j++) a0 += bf2f(gbuf[(size_t)srt[st + j] * OUT_DIM + l]);
        int n = nb + ns;
        if (n < N_NODES) {
            float res = (a0 + a1 + a2 + a3) / fmaxf((float)deg, 1.0f)
                      + rbuf[(size_t)n * OUT_DIM + l];
            size_t oi = (size_t)n * OUT_DIM + l;
            if (bfv) ((u16*)out)[oi] = f2bf(res);
            else     ((float*)out)[oi] = res;
        }
    }
}

extern "C" void kernel_launch(void* const* d_in, const int* in_sizes, int n_in,
                              void* d_out, int out_size, void* d_ws, size_t ws_size,
                              hipStream_t stream) {
    const void* x   = d_in[0];
    const int*  ei  = (const int*)d_in[1];
    const void* W1l = d_in[2];
    const void* b1  = d_in[3];
    const void* W1r = d_in[4];
    const void* W2l = d_in[5];
    const void* b2  = d_in[6];
    const void* W2r = d_in[7];

    // ws layout (4B units); total ~16.1 MB (ws >= 64.4 MB proven earlier)
    int* qcnt    = (int*)d_ws;                       // 8*QSTR (memset)
    float* tW1l  = (float*)(qcnt + 8 * QSTR);        // 2048
    float* tW1r  = tW1l + IN_DIM * HID_DIM;          // 2048
    float* tW2l  = tW1r + IN_DIM * HID_DIM;          // 512
    float* tW2r  = tW2l + HID_DIM * OUT_DIM;         // 512
    float* tb1   = tW2r + HID_DIM * OUT_DIM;         // 64
    float* tb2   = tb1 + HID_DIM;                    // 8
    u32* qbuf    = (u32*)(tb2 + OUT_DIM);            // 8*NBKT*QCP (11.2 MB)
    u16* gbuf    = (u16*)(qbuf + (size_t)8 * NBKT * QCP);      // N*8 u16 (1.6 MB)
    float* rbuf  = (float*)(gbuf + (size_t)N_NODES * OUT_DIM); // N*8 f32 (3.2 MB)

    // zero qcnt only (64 KB)
    hipMemsetAsync(d_ws, 0, 8 * QSTR * sizeof(int), stream);

    k_part2<<<NCHUNK, 256, 0, stream>>>(ei, (const u32*)x,
                                        W1l, b1, W1r, W2l, b2, W2r,
                                        qcnt, qbuf,
                                        tW1l, tW1r, tW2l, tW2r, tb1, tb2);
    k_l1<<<NBKT, 256, 0, stream>>>(x, qcnt, qbuf,
                                   tW1l, tW1r, tW2l, tW2r, tb1, tb2,
                                   gbuf, rbuf, (const u32*)x);
    k_l2<<<NBKT, 256, 0, stream>>>(gbuf, rbuf, qcnt, qbuf,
                                   (const u32*)x, d_out);
}